// Round 3
// baseline (290.882 us; speedup 1.0000x reference)
//
#include <hip/hip_runtime.h>

// SNN forward scan: B=64, N=1024, T=512. Row = (b*N+n), x[row*512 + t].
//
// R10: per-row-octet TIME SKEW on the R8 base (R9's occupancy loss reverted).
// Theory: channel = (8*row + chunk) mod nch for 256-B interleave @ 2-KiB row
// stride -> unskewed, every block at phase k hits only the channels with
// residue == k (mod 8): 8x concentration, globally lockstepped, plus one
// DRAM row-activation per 256-B granule on those channels (tFAW). Rows are
// scan-INDEPENDENT, so skew row-octet q = row>>3 by q chunks: row computes
// chunk c at phase k=c+q. Per phase a block then touches 8 different chunk
// offsets -> 8x more channel residues active, 8x lower per-channel
// activation rate. Zero LDS/occupancy cost: same 49.9-KiB 3-buffer layout,
// 3 blocks/CU, same 256-B granules, NT stores kept (R8: -9%).
// Cost: 15 phases (8 + 7 fill/drain) instead of 8; range checks are
// wave-uniform (k, it) -> scalar branches.
// Predicted: FETCH/WRITE unchanged; dur 85.7 -> 60-72 us if concentration
// theory right; 82-92 us falsifies it -> pivot to >=1-KiB granules or stop.
//
// io skew identity: io instr it covers rows {r4+4it}, r4 in 0..3, and
// (r4+4it)>>3 == it>>1 for r4<4 -> per-it skew q_it = it>>1 (compile-time).
//
// Schedule (phase k): row r (q=r>>3) chunk c=k-q computed from inbuf[k&1];
// stage writes chunk k+1-q into inbuf[(k+1)&1] (loaded during phase k-1);
// load issues chunk k+2-q; drain reads outbuf (written phase k-1's B) ->
// global chunk k-1-q. Each row runs the identical serial sequence ->
// BIT-EXACT vs float32 reference. __fmul_rn/__fadd_rn + contract(off).
#pragma clang fp contract(off)

#define ROWS    64                    // rows per block (1 compute wave)
#define T_LEN   512
#define CHUNK   64                    // timesteps per tile (256 B/row contiguous)
#define NCHUNK  (T_LEN / CHUNK)       // 8
#define NPHASE  (NCHUNK + 7)          // 15: chunk c of octet q runs at phase c+q
#define STRIDE  (CHUNK + 1)           // 65: odd -> conflict-free b32 LDS
#define NV      16                    // float4 per io-lane per chunk
#define NPARAM  1024

typedef float f4_nt __attribute__((ext_vector_type(4)));

// lgkmcnt(0)-only barrier: LDS visibility without the vmcnt(0) drain.
#define BARRIER() asm volatile("s_waitcnt lgkmcnt(0)\n\ts_barrier" ::: "memory")

__global__ __launch_bounds__(192) void snn_fwd(
    const float* __restrict__ x,
    const float* __restrict__ beta,
    const float* __restrict__ p,
    const float* __restrict__ bparam,
    float* __restrict__ out)
{
    __shared__ float inbuf[2][ROWS * STRIDE];  // 2 x 16,640 B
    __shared__ float outbuf[ROWS * STRIDE];    //     16,640 B  (49.9 KB total)

    const int tid     = threadIdx.x;
    const int wid     = tid >> 6;       // 0=compute, 1=load, 2=store
    const int lane    = tid & 63;
    const int rowBase = blockIdx.x * ROWS;

    const float4* __restrict__ xv = (const float4*)x;  // row stride 128 float4
    float4* __restrict__ ov       = (float4*)out;

    // io mapping: lane = r4*16 + t16. One instr: rows {r4+4*it}, 16 float4
    // (=256 B) contiguous per row. Chunk c adds c*NV float4.
    const int t16 = lane & 15;
    const int r4  = lane >> 4;
    const int gq  = (rowBase + r4) * (T_LEN / 4) + t16;  // float4 units
    const int lf  = r4 * STRIDE + t16 * 4;               // float units

    // compute state
    float mem = 0.0f, refac = 2.0f, a = 0.0f, vth = 1.0f, ps = 0.0f;
    float beta_c = 0.f, p_c = 0.f, b_c = 0.f;
    const int cb = lane * STRIDE;  // compute lane's LDS row
    const int cq = lane >> 3;      // compute lane's skew (chunks)

    if (wid == 0) {
        const int n = (rowBase + lane) & (NPARAM - 1);
        beta_c = fminf(fmaxf(beta[n], 0.001f), 0.999f);
        p_c    = fminf(fabsf(p[n]), 0.999f);
        b_c    = fminf(fmaxf(fabsf(bparam[n]), 0.001f), 1.0f);
    }

    auto step = [&](float xt) -> float {
        refac = (ps > 0.0f) ? 0.0f : refac;           // spike-triggered reset
        const float ic = (refac < 2.0f) ? 0.0f : xt;  // refractory input mask
        refac += 1.0f;
        const float nm   = __fadd_rn(__fmul_rn(mem, beta_c), ic);  // integrate
        const float diff = __fsub_rn(nm, vth);
        const float s    = (diff > 0.0f) ? 1.0f : 0.0f;
        mem = (diff > 0.0f) ? 0.0f : nm;              // reset-to-zero on spike
        a   = __fadd_rn(__fmul_rn(p_c, a), s);        // adaptation
        vth = __fadd_rn(1.0f, __fmul_rn(b_c, a));     // adaptive threshold
        ps  = s;
        return s;
    };

    float4 ld[NV];  // load wave's register pipeline (one phase ahead)

    // issue loads for phase kp: instr it fetches chunk c = kp+2-(it>>1)
    auto loadPhase = [&](int kp) {
        #pragma unroll
        for (int it = 0; it < NV; ++it) {
            const int c = kp + 2 - (it >> 1);
            if (0 <= c && c < NCHUNK)
                ld[it] = xv[gq + c * NV + it * 4 * (T_LEN / 4)];  // +4 rows/it
        }
    };
    // stage regs (loaded during phase kp-1) into inbuf[buf]: c = kp+1-(it>>1)
    auto stagePhase = [&](int kp, int buf) {
        #pragma unroll
        for (int it = 0; it < NV; ++it) {
            const int c = kp + 1 - (it >> 1);   // same validity as the load
            if (0 <= c && c < NCHUNK) {
                const int o = lf + it * 4 * STRIDE;
                inbuf[buf][o + 0] = ld[it].x;
                inbuf[buf][o + 1] = ld[it].y;
                inbuf[buf][o + 2] = ld[it].z;
                inbuf[buf][o + 3] = ld[it].w;
            }
        }
    };
    // drain spikes computed at phase kp-1: chunk c = kp-1-(it>>1), NT stores
    auto drainPhase = [&](int kp) {
        #pragma unroll
        for (int it = 0; it < NV; ++it) {
            const int c = kp - 1 - (it >> 1);
            if (0 <= c && c < NCHUNK) {
                const int o = lf + it * 4 * STRIDE;
                float4 sv;
                sv.x = outbuf[o + 0];
                sv.y = outbuf[o + 1];
                sv.z = outbuf[o + 2];
                sv.w = outbuf[o + 3];
                __builtin_nontemporal_store(
                    *reinterpret_cast<f4_nt*>(&sv),
                    reinterpret_cast<f4_nt*>(&ov[gq + c * NV + it * 4 * (T_LEN / 4)]));
            }
        }
    };

    // preamble: phase-0 chunks staged into inbuf[0]; phase-1 chunks in regs
    if (wid == 1) {
        loadPhase(-2);        // q=0: chunk 0
        stagePhase(-1, 0);    // stage it -> inbuf[0]
        loadPhase(-1);        // q=0: chunk 1, q=1: chunk 0
    }
    BARRIER();

    #pragma unroll 1
    for (int k = 0; k < NPHASE; ++k) {
        const int cur = k & 1;
        float sv[CHUNK];
        const int  cc  = k - cq;                         // this lane's chunk
        const bool act = (wid == 0) & (cc >= 0) & (cc < NCHUNK);
        // ---- phase A ----
        if (wid == 0) {
            if (act) {
                #pragma unroll
                for (int t = 0; t < CHUNK; ++t)
                    sv[t] = step(inbuf[cur][cb + t]);
            }
        } else if (wid == 1) {
            stagePhase(k, cur ^ 1);   // regs loaded one phase ago
            loadPhase(k);             // refill register pipeline
        } else {
            drainPhase(k);            // spikes written in phase k-1's B
        }
        BARRIER();  // store's outbuf reads done; inbuf[cur^1] staged
        // ---- phase B ----
        if (act) {
            #pragma unroll
            for (int t = 0; t < CHUNK; ++t)
                outbuf[cb + t] = sv[t];
        }
        BARRIER();  // outbuf visible to store wave next phase
    }
    if (wid == 2) drainPhase(NPHASE);  // q=7's chunk 7 (computed at phase 14)
}

extern "C" void kernel_launch(void* const* d_in, const int* in_sizes, int n_in,
                              void* d_out, int out_size, void* d_ws, size_t ws_size,
                              hipStream_t stream) {
    const float* x    = (const float*)d_in[0];
    const float* beta = (const float*)d_in[1];
    const float* p    = (const float*)d_in[2];
    const float* b    = (const float*)d_in[3];
    float* out        = (float*)d_out;

    const int BN = 64 * 1024;  // rows
    snn_fwd<<<dim3(BN / ROWS), dim3(192), 0, stream>>>(x, beta, p, b, out);
}